// Round 11
// baseline (36.012 us; speedup 1.0000x reference)
//
#include <hip/hip_runtime.h>
#include <hip/hip_bf16.h>

typedef __attribute__((ext_vector_type(4))) float float4v;

// EXACT chain validated at absmax 0.0 (R8/R10): Cephes f32 log (serial FMA
// Horner, 0.693359375 / -2.12194440e-4 split), f32 divide by RN32(ln2), floorf.
__device__ __forceinline__ float np_logf(float xin) {
  union { float f; unsigned u; } v; v.f = xin;
  int e = (int)(v.u >> 23) - 126;
  v.u = (v.u & 0x007fffffu) | 0x3f000000u;
  float m = v.f;
  if (m < 0.70710678118654752440f) { e -= 1; m = m + m; }
  m = m - 1.0f;
  float p = 7.0376836292e-2f;
  p = fmaf(p, m, -1.1514610310e-1f);
  p = fmaf(p, m,  1.1676998740e-1f);
  p = fmaf(p, m, -1.2420140846e-1f);
  p = fmaf(p, m,  1.4249322787e-1f);
  p = fmaf(p, m, -1.6668057665e-1f);
  p = fmaf(p, m,  2.0000714765e-1f);
  p = fmaf(p, m, -2.4999993993e-1f);
  p = fmaf(p, m,  3.3333331174e-1f);
  float z = m * m;
  float y = (p * m) * z;
  float fe = (float)e;
  y = fmaf(fe, -2.12194440e-4f, y);
  y = fmaf(-0.5f, z, y);
  float r = m + y;
  r = fmaf(fe, 0.693359375f, r);
  return r;
}

__device__ __forceinline__ int chain_bucket(unsigned xa, int NBUCK) {
  float lx = np_logf((float)xa);                // exact int->f32 (xa < 2^24)
  float q = lx / 0.6931471824645996f;           // f32 divide, RN32(ln2)
  int bb = (int)floorf(q);
  return min(max(bb, 0), NBUCK);
}

// out[b,i,j] = pos_w[j-i+N-1] + ts_w[bucket(ts[b,min(i+1,N-1)] - ts[b,j])]
// bucket == msb(xa) except within +-256 of 2^m (17x margin vs max chain error;
// validated end-to-end at absmax 0.0 in R9/R10). Near-test hoisted to a
// WAVE-UNIFORM branch; chain is exact everywhere so the taken arm is trivially
// correct for all lanes.
__global__ __launch_bounds__(256) void bias_kernel(
    const int* __restrict__ ts, const float* __restrict__ ts_w,
    const float* __restrict__ pos_w,
    float* __restrict__ out, int N, int NB1) {
  __shared__ float sW[512];
  const int tid = threadIdx.x;
  for (int k = tid; k < NB1 && k < 512; k += 256) sW[k] = ts_w[k];
  __syncthreads();

  const int i = blockIdx.x;   // output row
  const int b = blockIdx.y;   // batch
  const int NBUCK = NB1 - 1;

  const int* tsrow = ts + (size_t)b * N;
  const int tip1 = tsrow[min(i + 1, N - 1)];     // ext[:,1:], last repeated
  const float* pw = pos_w + (N - 1 - i);         // pw[j] = pos_w[j - i + N - 1]
  float* orow = out + ((size_t)b * N + i) * N;

  const int lane = tid & 63;
  const int wv = tid >> 6;                       // wave id 0..3

  // Each segment = 256 consecutive columns handled by one wave:
  // lane l owns j0 = seg*256 + 4l .. +3  (16B-aligned -> dwordx4 load/store).
  for (int seg = wv; seg * 256 < N; seg += 4) {
    const int j0 = seg * 256 + lane * 4;
    int4 t4 = *reinterpret_cast<const int4*>(tsrow + j0);
    int tv[4] = {t4.x, t4.y, t4.z, t4.w};

    unsigned xa[4]; int kk[4]; bool near = false;
#pragma unroll
    for (int e = 0; e < 4; ++e) {
      int d = tip1 - tv[e];
      unsigned a = (unsigned)(d < 0 ? -d : d);
      a |= (unsigned)(a == 0);                   // max(|d|,1), < 2^24
      xa[e] = a;
      int k = 31 - __clz((int)a);
      kk[e] = k;
      unsigned lo = a - (1u << k);
      unsigned hi = (2u << k) - a;
      near |= (lo < 256u) | (hi <= 256u);
    }

    float4v st;
    if (__any(near)) {                           // wave-uniform branch
#pragma unroll
      for (int e = 0; e < 4; ++e)
        st[e] = pw[j0 + e] + sW[chain_bucket(xa[e], NBUCK)];
    } else {
#pragma unroll
      for (int e = 0; e < 4; ++e)
        st[e] = pw[j0 + e] + sW[min(kk[e], NBUCK)];
    }
    // Output is write-once, never re-read: bypass L2 with nontemporal store.
    __builtin_nontemporal_store(st, reinterpret_cast<float4v*>(orow + j0));
  }
}

extern "C" void kernel_launch(void* const* d_in, const int* in_sizes, int n_in,
                              void* d_out, int out_size, void* d_ws, size_t ws_size,
                              hipStream_t stream) {
  // Identify inputs BY SIZE: timestamps = largest, ts_w = smallest, pos_w = middle.
  int i_ts = 0;
  if (in_sizes[1] > in_sizes[i_ts]) i_ts = 1;
  if (in_sizes[2] > in_sizes[i_ts]) i_ts = 2;
  int i_tsw = 0;
  if (in_sizes[1] < in_sizes[i_tsw]) i_tsw = 1;
  if (in_sizes[2] < in_sizes[i_tsw]) i_tsw = 2;
  int i_pw = 3 - i_ts - i_tsw;

  const int* ts = (const int*)d_in[i_ts];          // int32 on device
  const float* ts_w = (const float*)d_in[i_tsw];   // f32
  const float* pos_w = (const float*)d_in[i_pw];   // f32

  const int NB1 = in_sizes[i_tsw];           // NUM_BUCKETS + 1
  const int N = (in_sizes[i_pw] + 1) / 2;    // pos_w has 2N-1
  const int B = in_sizes[i_ts] / N;

  dim3 grid(N, B);
  bias_kernel<<<grid, 256, 0, stream>>>(ts, ts_w, pos_w,
                                        (float*)d_out, N, NB1);
}